// Round 8
// baseline (29.908 us; speedup 1.0000x reference)
//
#include <hip/hip_runtime.h>

#define W      1024
#define NROWS  16384            // 16 * 1 * 1024
#define NPIX   16777216.0       // 16 * 1024 * 1024
#define EPSF   1e-5f
#define PX     16               // pixels per lane: 64 lanes * 16 = full row
#define RPW    4                // rows per wave (depth-2 register pipeline)
#define NWAVES (NROWS / RPW)    // 4096
#define NBLOCKS (NWAVES / 4)    // 1024 blocks of 4 waves

typedef float f32x4 __attribute__((ext_vector_type(4)));

// Issue 8 global_load_dwordx4 (one row of I and J) into 8 named SSA vectors.
// Results are NOT ready at asm end — they land when vmcnt drains. The ONLY
// use of these values before the matching RELEASE8 is that RELEASE8 itself.
// NOTE: requires a VGPR budget with NO spilling anywhere in the kernel —
// a spill store would read a pending register AND alias vmcnt counting.
// Hence __launch_bounds__(256,2): 256-VGPR cap, ~200 live peak, no spills.
#define LOAD8(pi, pj, a0, a1, a2, a3, b0, b1, b2, b3)                  \
    asm volatile(                                                      \
        "global_load_dwordx4 %0, %8, off\n\t"                          \
        "global_load_dwordx4 %1, %8, off offset:16\n\t"                \
        "global_load_dwordx4 %2, %8, off offset:32\n\t"                \
        "global_load_dwordx4 %3, %8, off offset:48\n\t"                \
        "global_load_dwordx4 %4, %9, off\n\t"                          \
        "global_load_dwordx4 %5, %9, off offset:16\n\t"                \
        "global_load_dwordx4 %6, %9, off offset:32\n\t"                \
        "global_load_dwordx4 %7, %9, off offset:48\n\t"                \
        : "=&v"(a0), "=&v"(a1), "=&v"(a2), "=&v"(a3),                  \
          "=&v"(b0), "=&v"(b1), "=&v"(b2), "=&v"(b3)                   \
        : "v"(pi), "v"(pj)                                             \
        : "memory")

// Wait until <=N of our loads are outstanding (in-order retirement) and
// redefine the row's 8 vectors (tied "+v": same physical reg, no copies) so
// all consumers data-depend on post-wait values. sched_barrier stops VALU
// hoisting above the wait (rule #18).
#define RELEASE8(N, a0, a1, a2, a3, b0, b1, b2, b3)                    \
    do {                                                               \
        asm volatile("s_waitcnt vmcnt(" #N ")"                         \
                     : "+v"(a0), "+v"(a1), "+v"(a2), "+v"(a3),         \
                       "+v"(b0), "+v"(b1), "+v"(b2), "+v"(b3)          \
                     :: "memory");                                     \
        __builtin_amdgcn_sched_barrier(0);                             \
    } while (0)

// One row's cc partial from its 8 float4s (16 px/lane), all by value (SSA).
// Halo via lane shuffles; zeros at row ends.
__device__ __forceinline__ float row_cc(f32x4 A0, f32x4 A1, f32x4 A2, f32x4 A3,
                                        f32x4 B0, f32x4 B1, f32x4 B2, f32x4 B3,
                                        int lane) {
    float AL[4], AR[4], BL[4], BR[4];
#pragma unroll
    for (int i = 0; i < 4; ++i) {
        AL[i] = __shfl_up(A3[i], 1, 64);
        BL[i] = __shfl_up(B3[i], 1, 64);
        AR[i] = __shfl_down(A0[i], 1, 64);
        BR[i] = __shfl_down(B0[i], 1, 64);
    }
    if (lane == 0) {
#pragma unroll
        for (int i = 0; i < 4; ++i) { AL[i] = 0.f; BL[i] = 0.f; }
    }
    if (lane == 63) {
#pragma unroll
        for (int i = 0; i < 4; ++i) { AR[i] = 0.f; BR[i] = 0.f; }
    }

    // Window: [0..3]=left halo, [4..19]=own 16, [20..23]=right halo.
    float a[24], b[24];
#pragma unroll
    for (int i = 0; i < 4; ++i) {
        a[i]      = AL[i];   b[i]      = BL[i];
        a[4 + i]  = A0[i];   b[4 + i]  = B0[i];
        a[8 + i]  = A1[i];   b[8 + i]  = B1[i];
        a[12 + i] = A2[i];   b[12 + i] = B2[i];
        a[16 + i] = A3[i];   b[16 + i] = B3[i];
        a[20 + i] = AR[i];   b[20 + i] = BR[i];
    }

    float sAc = 0.f, sBc = 0.f, sAA = 0.f, sBB = 0.f, sAB = 0.f;
#pragma unroll
    for (int k = 0; k < 9; ++k) {
        sAc += a[k];
        sBc += b[k];
        sAA = fmaf(a[k], a[k], sAA);
        sBB = fmaf(b[k], b[k], sBB);
        sAB = fmaf(a[k], b[k], sAB);
    }

    const float ninv = -(1.f / 9.f);
    float acc = 0.f;
#pragma unroll
    for (int p = 0; p < PX; ++p) {
        const float cross = fmaf(sAc * sBc, ninv, sAB);
        const float varA  = fmaf(sAc * sAc, ninv, sAA);
        const float varB  = fmaf(sBc * sBc, ninv, sBB);
        const float denom = fmaf(varA, varB, EPSF);
        acc += (cross * cross) * __builtin_amdgcn_rcpf(denom);
        if (p < PX - 1) {
            const float an = a[9 + p], ao = a[p];
            const float bn = b[9 + p], bo = b[p];
            sAc += an - ao;
            sBc += bn - bo;
            sAA = fmaf(an, an, sAA); sAA = fmaf(ao, -ao, sAA);
            sBB = fmaf(bn, bn, sBB); sBB = fmaf(bo, -bo, sBB);
            sAB = fmaf(an, bn, sAB); sAB = fmaf(ao, -bo, sAB);
        }
    }
    return acc;
}

// One wave per 4 consecutive rows, depth-2 asm pipeline:
//   L(r0) L(r1) | w8 C(r0) L(r2) | w8 C(r1) L(r3) | w8 C(r2) | w0 C(r3)
// All LOAD8/RELEASE8 are volatile asm -> fixed mutual order -> exact vmcnt.
// 256-VGPR budget (launch_bounds 256,2): no spills, so scratch never touches
// vmcnt and no pending register is ever copied.
__global__ __launch_bounds__(256, 2) void lncc_rows(const float* __restrict__ I,
                                                    const float* __restrict__ J,
                                                    float* __restrict__ partials) {
    const int lane = threadIdx.x & 63;
    const int wid  = (blockIdx.x << 2) | (threadIdx.x >> 6);   // 0..4095
    const size_t base = (size_t)wid * RPW * W + (size_t)lane * PX;
    const float* pI0 = I + base;
    const float* pJ0 = J + base;

    f32x4 xA0, xA1, xA2, xA3, xB0, xB1, xB2, xB3;   // even rows
    f32x4 yA0, yA1, yA2, yA3, yB0, yB1, yB2, yB3;   // odd rows

    LOAD8(pI0,     pJ0,     xA0, xA1, xA2, xA3, xB0, xB1, xB2, xB3);   // r0
    LOAD8(pI0 + W, pJ0 + W, yA0, yA1, yA2, yA3, yB0, yB1, yB2, yB3);   // r1

    RELEASE8(8, xA0, xA1, xA2, xA3, xB0, xB1, xB2, xB3);               // r0 landed
    float acc = row_cc(xA0, xA1, xA2, xA3, xB0, xB1, xB2, xB3, lane);

    __builtin_amdgcn_sched_barrier(0);
    LOAD8(pI0 + 2 * W, pJ0 + 2 * W, xA0, xA1, xA2, xA3, xB0, xB1, xB2, xB3); // r2

    RELEASE8(8, yA0, yA1, yA2, yA3, yB0, yB1, yB2, yB3);               // r1 landed
    acc += row_cc(yA0, yA1, yA2, yA3, yB0, yB1, yB2, yB3, lane);

    __builtin_amdgcn_sched_barrier(0);
    LOAD8(pI0 + 3 * W, pJ0 + 3 * W, yA0, yA1, yA2, yA3, yB0, yB1, yB2, yB3); // r3

    RELEASE8(8, xA0, xA1, xA2, xA3, xB0, xB1, xB2, xB3);               // r2 landed
    acc += row_cc(xA0, xA1, xA2, xA3, xB0, xB1, xB2, xB3, lane);

    RELEASE8(0, yA0, yA1, yA2, yA3, yB0, yB1, yB2, yB3);               // r3 landed
    acc += row_cc(yA0, yA1, yA2, yA3, yB0, yB1, yB2, yB3, lane);

    // Deterministic wave reduction, one partial per wave.
#pragma unroll
    for (int off = 32; off > 0; off >>= 1)
        acc += __shfl_down(acc, off, 64);
    if (lane == 0) partials[wid] = acc;
}

// Deterministic finalize: 256 threads x 16 partials (4 float4, unrolled),
// double accum, fixed-order LDS tree.
__global__ __launch_bounds__(256) void lncc_finalize(const float* __restrict__ partials,
                                                     float* __restrict__ out) {
    __shared__ double sh[256];
    const int t = threadIdx.x;
    double s = 0.0;
#pragma unroll
    for (int c = 0; c < 4; ++c) {
        const float4 v = *(const float4*)(partials + (size_t)t * 16 + c * 4);
        s += ((double)v.x + (double)v.y) + ((double)v.z + (double)v.w);
    }
    sh[t] = s;
    __syncthreads();
#pragma unroll
    for (int off = 128; off > 0; off >>= 1) {
        if (t < off) sh[t] += sh[t + off];
        __syncthreads();
    }
    if (t == 0) out[0] = (float)(1.0 - sh[0] / NPIX);
}

extern "C" void kernel_launch(void* const* d_in, const int* in_sizes, int n_in,
                              void* d_out, int out_size, void* d_ws, size_t ws_size,
                              hipStream_t stream) {
    const float* I = (const float*)d_in[0];
    const float* J = (const float*)d_in[1];
    float* partials = (float*)d_ws;          // 4096 floats = 16 KiB scratch
    float* out      = (float*)d_out;

    lncc_rows<<<NBLOCKS, 256, 0, stream>>>(I, J, partials);
    lncc_finalize<<<1, 256, 0, stream>>>(partials, out);
}